// Round 2
// baseline (54813.446 us; speedup 1.0000x reference)
//
#include <hip/hip_runtime.h>
#include <hip/hip_bf16.h>
#include <math.h>

#define T_DIM 512
#define B_DIM 64
#define I_DIM 1024
#define H_DIM 1024

// d_out layout (flat f32): ys [T][B][2H], hT_f [B][H], cT_f, hT_b, cT_b
#define OUT_HTF (T_DIM * B_DIM * 2 * H_DIM)
#define OUT_CTF (OUT_HTF + B_DIM * H_DIM)
#define OUT_HTB (OUT_CTF + B_DIM * H_DIM)
#define OUT_CTB (OUT_HTB + B_DIM * H_DIM)

__device__ __forceinline__ float sigmoidf_(float v) {
    return 1.0f / (1.0f + expf(-v));
}

template <typename GT>
__device__ __forceinline__ float4 load4g(const GT* p) {
    if constexpr (sizeof(GT) == 4) {
        return *reinterpret_cast<const float4*>(p);
    } else {
        const __hip_bfloat16* b = reinterpret_cast<const __hip_bfloat16*>(p);
        __hip_bfloat16 tmp[4];
        *reinterpret_cast<uint2*>(tmp) = *reinterpret_cast<const uint2*>(b);
        return make_float4(__bfloat162float(tmp[0]), __bfloat162float(tmp[1]),
                           __bfloat162float(tmp[2]), __bfloat162float(tmp[3]));
    }
}

template <typename GT>
__device__ __forceinline__ void store8g(GT* p, const float* v) {
    if constexpr (sizeof(GT) == 4) {
        *reinterpret_cast<float4*>(p)     = make_float4(v[0], v[1], v[2], v[3]);
        *reinterpret_cast<float4*>(p + 4) = make_float4(v[4], v[5], v[6], v[7]);
    } else {
        __hip_bfloat16 tmp[8];
#pragma unroll
        for (int i = 0; i < 8; ++i) tmp[i] = __float2bfloat16(v[i]);
        *reinterpret_cast<float4*>(p) = *reinterpret_cast<float4*>(tmp);
    }
}

// ---------------------------------------------------------------------------
// Phase 1: gx[dir][T*B][4H] = x @ W_ih^T + (b_ih + b_hh)
// Grid: x = 64 (32 n-tiles * 2 dirs), y = 512 (m-tiles of 64 rows over T*B).
// Block: 256 threads, tile 64x128, thread tile 4m x 8j.
// LDS: 2 x [64][128] f32 double-buffered = 64KB -> 2 blocks/CU.
// ---------------------------------------------------------------------------
template <typename GT>
__global__ __launch_bounds__(256) void xproj_gemm(
    const float* __restrict__ x,
    const float* __restrict__ wihf, const float* __restrict__ bihf,
    const float* __restrict__ bhhf,
    const float* __restrict__ wihb, const float* __restrict__ bihb,
    const float* __restrict__ bhhb,
    GT* __restrict__ gx)
{
    __shared__ float smem[2 * 64 * 128];

    const int tid = threadIdx.x;
    const int nb  = blockIdx.x;          // n-tile + dir (x fastest -> same m-panel reused)
    const int dir = nb >> 5;
    const int n0  = (nb & 31) * 128;
    const int m0  = blockIdx.y * 64;     // rows in flattened [T*B]

    const float* w  = dir ? wihb : wihf;
    const float* bi = dir ? bihb : bihf;
    const float* bh = dir ? bhhb : bhhf;
    const float* A  = x + (size_t)m0 * I_DIM;

    const int jp = tid >> 4;             // 0..15 -> cols jp*8 .. jp*8+7
    const int mg = tid & 15;             // 0..15 -> rows mg*4 .. mg*4+3
    const int j0 = n0 + jp * 8;          // global gate-col base

    float acc[4][8] = {};
    float4 ld[8];

    auto issue_loads = [&](int kc) {
        const int kb = kc * 128;
#pragma unroll
        for (int p = 0; p < 8; ++p) {
            const int e = p * 256 + tid;
            const int m = e >> 5;
            const int q = e & 31;
            ld[p] = *reinterpret_cast<const float4*>(A + (size_t)m * I_DIM + kb + q * 4);
        }
    };
    auto write_smem = [&](int buf) {
        float* dst = smem + buf * 8192;
#pragma unroll
        for (int p = 0; p < 8; ++p) {
            const int e = p * 256 + tid;
            const int m = e >> 5;
            const int q = e & 31;
            const int qs = q ^ ((m >> 2) & 7);
            *reinterpret_cast<float4*>(&dst[m * 128 + qs * 4]) = ld[p];
        }
    };
    auto compute = [&](int kc, int buf) {
        const int kb = kc * 128;
        const float* wp = w + (size_t)j0 * 1024 + kb;
        const float* sb = smem + buf * 8192 + (mg * 4) * 128;
#pragma unroll 2
        for (int q = 0; q < 32; ++q) {
            const int qs = (q ^ (mg & 7)) * 4;
            float4 a[4];
#pragma unroll
            for (int i = 0; i < 4; ++i)
                a[i] = *reinterpret_cast<const float4*>(&sb[i * 128 + qs]);
#pragma unroll
            for (int cj = 0; cj < 8; ++cj) {
                const float4 wv =
                    *reinterpret_cast<const float4*>(wp + (size_t)cj * 1024 + q * 4);
#pragma unroll
                for (int i = 0; i < 4; ++i) {
                    acc[i][cj] = fmaf(a[i].x, wv.x, fmaf(a[i].y, wv.y,
                                 fmaf(a[i].z, wv.z, fmaf(a[i].w, wv.w, acc[i][cj]))));
                }
            }
        }
    };

    issue_loads(0);
    write_smem(0);
    __syncthreads();
    for (int kc = 0; kc < 8; ++kc) {
        if (kc < 7) issue_loads(kc + 1);
        compute(kc, kc & 1);
        __syncthreads();
        if (kc < 7) {
            write_smem((kc + 1) & 1);
            __syncthreads();
        }
    }

    // epilogue: + bias, store 4 rows x 8 cols
    float bias[8];
#pragma unroll
    for (int cj = 0; cj < 8; ++cj) bias[cj] = bi[j0 + cj] + bh[j0 + cj];

    GT* gbase = gx + (size_t)dir * (32768ull * 4096ull);
#pragma unroll
    for (int i = 0; i < 4; ++i) {
        const int row = m0 + mg * 4 + i;
        float v[8];
#pragma unroll
        for (int cj = 0; cj < 8; ++cj) v[cj] = acc[i][cj] + bias[cj];
        store8g(gbase + (size_t)row * 4096 + j0, v);
    }
}

// ---------------------------------------------------------------------------
// Step kernel: gates = gx[t] + h_prev @ W_hh^T ; then LSTM cell update.
// Grid: 512 blocks = dir(2) x mh(2) x u-slice(128). 256 threads.
// Block tile: 32 batch rows x 32 gate cols ({i,f,g,o} x 8 units).
// Thread tile: 1m x 4j. LDS: 2 x [32][128] f32 = 32KB -> 2 blocks/CU (8 waves).
// ---------------------------------------------------------------------------
template <typename GT>
__global__ __launch_bounds__(256) void lstm_step_h(
    const float* __restrict__ h0f, const float* __restrict__ c0f,
    const float* __restrict__ h0b, const float* __restrict__ c0b,
    const float* __restrict__ whhf, const float* __restrict__ whhb,
    const GT* __restrict__ gx,
    float* __restrict__ out, int step)
{
    __shared__ float smem[2 * 32 * 128];

    const int tid = threadIdx.x;
    const int bid = blockIdx.x;
    const int dir = bid >> 8;
    const int mh  = (bid >> 7) & 1;
    const int u0  = (bid & 127) * 8;
    const int t   = dir ? (T_DIM - 1 - step) : step;
    const int m0  = mh * 32;

    const float* whh = dir ? whhb : whhf;

    const float* hprev;
    int hst;
    if (step == 0) {
        hprev = dir ? h0b : h0f;
        hst = H_DIM;
    } else {
        const int tprev = dir ? (t + 1) : (t - 1);
        hprev = out + (size_t)tprev * B_DIM * 2 * H_DIM + dir * H_DIM;
        hst = 2 * H_DIM;
    }

    const int jp = tid >> 5;             // 0..7 -> cols jp*4 .. jp*4+3
    const int mg = tid & 31;             // row
    // block-local col c = jp*4+ci ; gate g = jp>>1 ; unit = (jp&1)*4 + ci
    const int j_base = (jp >> 1) * H_DIM + u0 + (jp & 1) * 4;

    float acc[4] = {0.f, 0.f, 0.f, 0.f};
    float4 ld[4];

    auto issue_loads = [&](int kc) {
        const int kb = kc * 128;
#pragma unroll
        for (int p = 0; p < 4; ++p) {
            const int e = p * 256 + tid;
            const int m = e >> 5;        // 0..31
            const int q = e & 31;
            ld[p] = *reinterpret_cast<const float4*>(
                hprev + (size_t)(m0 + m) * hst + kb + q * 4);
        }
    };
    auto write_smem = [&](int buf) {
        float* dst = smem + buf * 4096;
#pragma unroll
        for (int p = 0; p < 4; ++p) {
            const int e = p * 256 + tid;
            const int m = e >> 5;
            const int q = e & 31;
            const int qs = q ^ ((m >> 2) & 7);
            *reinterpret_cast<float4*>(&dst[m * 128 + qs * 4]) = ld[p];
        }
    };
    auto compute = [&](int kc, int buf) {
        const int kb = kc * 128;
        const float* wp = whh + (size_t)j_base * 1024 + kb;
        const float* sb = smem + buf * 4096 + mg * 128;
#pragma unroll 4
        for (int q = 0; q < 32; ++q) {
            const int qs = (q ^ ((mg >> 2) & 7)) * 4;
            const float4 a = *reinterpret_cast<const float4*>(&sb[qs]);
#pragma unroll
            for (int ci = 0; ci < 4; ++ci) {
                const float4 wv =
                    *reinterpret_cast<const float4*>(wp + (size_t)ci * 1024 + q * 4);
                acc[ci] = fmaf(a.x, wv.x, fmaf(a.y, wv.y,
                          fmaf(a.z, wv.z, fmaf(a.w, wv.w, acc[ci]))));
            }
        }
    };

    issue_loads(0);
    write_smem(0);
    __syncthreads();
    for (int kc = 0; kc < 8; ++kc) {
        if (kc < 7) issue_loads(kc + 1);
        compute(kc, kc & 1);
        __syncthreads();
        if (kc < 7) {
            write_smem((kc + 1) & 1);
            __syncthreads();
        }
    }

    // gx term (biases folded in phase 1)
    const GT* gsl = gx + (size_t)dir * (32768ull * 4096ull)
                    + (size_t)(t * 64 + m0 + mg) * 4096 + j_base;
    const float4 gxv = load4g(gsl);

    // gate exchange: gates[c 0..31][m 0..31], stride 33 (reuse smem)
    const int c0 = jp * 4;
    smem[(c0 + 0) * 33 + mg] = acc[0] + gxv.x;
    smem[(c0 + 1) * 33 + mg] = acc[1] + gxv.y;
    smem[(c0 + 2) * 33 + mg] = acc[2] + gxv.z;
    smem[(c0 + 3) * 33 + mg] = acc[3] + gxv.w;
    __syncthreads();

    // cell update: 32 rows x 8 units = 256 cells, 1 per thread
    const int du = tid >> 5;             // unit offset 0..7
    const int m  = tid & 31;             // local batch row
    const int b  = m0 + m;
    const int u  = u0 + du;

    const float ig = smem[(0 * 8 + du) * 33 + m];
    const float fg = smem[(1 * 8 + du) * 33 + m];
    const float gg = smem[(2 * 8 + du) * 33 + m];
    const float og = smem[(3 * 8 + du) * 33 + m];

    float* cslot = out + (dir ? OUT_CTB : OUT_CTF);
    float* hslot = out + (dir ? OUT_HTB : OUT_HTF);
    const float* cinit = dir ? c0b : c0f;

    const float cp = (step == 0) ? cinit[b * H_DIM + u] : cslot[b * H_DIM + u];
    const float cn = sigmoidf_(fg) * cp + sigmoidf_(ig) * tanhf(gg);
    const float h  = sigmoidf_(og) * tanhf(cn);
    cslot[b * H_DIM + u] = cn;
    out[(size_t)t * B_DIM * 2 * H_DIM + b * 2 * H_DIM + dir * H_DIM + u] = h;
    if (step == T_DIM - 1) hslot[b * H_DIM + u] = h;
}

// ---------------------------------------------------------------------------
// Fallback: round-1 monolithic per-step kernel (used only if ws too small)
// ---------------------------------------------------------------------------
__global__ __launch_bounds__(256) void lstm_step_mono(
    const float* __restrict__ x,
    const float* __restrict__ h0f, const float* __restrict__ c0f,
    const float* __restrict__ h0b, const float* __restrict__ c0b,
    const float* __restrict__ wihf, const float* __restrict__ whhf,
    const float* __restrict__ bihf, const float* __restrict__ bhhf,
    const float* __restrict__ wihb, const float* __restrict__ whhb,
    const float* __restrict__ bihb, const float* __restrict__ bhhb,
    float* __restrict__ out, int step)
{
    __shared__ float smem[2 * 64 * 128];

    const int tid = threadIdx.x;
    const int bid = blockIdx.x;
    const int dir = bid >> 7;
    const int u0  = (bid & 127) * 8;
    const int t   = dir ? (T_DIM - 1 - step) : step;

    const float* w_ih = dir ? wihb : wihf;
    const float* w_hh = dir ? whhb : whhf;
    const float* xt   = x + (size_t)t * B_DIM * I_DIM;

    const float* hprev;
    int hst;
    if (step == 0) {
        hprev = dir ? h0b : h0f;
        hst = H_DIM;
    } else {
        const int tprev = dir ? (t + 1) : (t - 1);
        hprev = out + (size_t)tprev * B_DIM * 2 * H_DIM + dir * H_DIM;
        hst = 2 * H_DIM;
    }

    const int jp = tid >> 4;
    const int mg = tid & 15;
    const int c0 = jp * 2;
    const int j0 = (c0 >> 3) * H_DIM + u0 + (c0 & 7);

    float acc[4][2];
#pragma unroll
    for (int i = 0; i < 4; ++i) { acc[i][0] = 0.f; acc[i][1] = 0.f; }

    float4 ld[8];

    auto issue_loads = [&](int kc) {
        const bool isX = (kc < 8);
        const float* src = isX ? xt : hprev;
        const int stride = isX ? I_DIM : hst;
        const int kb = (isX ? kc : (kc - 8)) * 128;
#pragma unroll
        for (int p = 0; p < 8; ++p) {
            const int e = p * 256 + tid;
            const int m = e >> 5;
            const int q = e & 31;
            ld[p] = *reinterpret_cast<const float4*>(
                src + (size_t)m * stride + kb + q * 4);
        }
    };
    auto write_smem = [&](int buf) {
        float* dst = smem + buf * 8192;
#pragma unroll
        for (int p = 0; p < 8; ++p) {
            const int e = p * 256 + tid;
            const int m = e >> 5;
            const int q = e & 31;
            const int qs = q ^ ((m >> 2) & 7);
            *reinterpret_cast<float4*>(&dst[m * 128 + qs * 4]) = ld[p];
        }
    };
    auto compute = [&](int kc, int buf) {
        const bool isX = (kc < 8);
        const int kb = (isX ? kc : (kc - 8)) * 128;
        const float* wp0 = (isX ? w_ih : w_hh) + (size_t)j0 * 1024 + kb;
        const float* wp1 = wp0 + 1024;
        const float* sb = smem + buf * 8192 + (mg * 4) * 128;
#pragma unroll 4
        for (int q = 0; q < 32; ++q) {
            const float4 w0 = *reinterpret_cast<const float4*>(wp0 + q * 4);
            const float4 w1 = *reinterpret_cast<const float4*>(wp1 + q * 4);
            const int qs = (q ^ (mg & 7)) * 4;
#pragma unroll
            for (int i = 0; i < 4; ++i) {
                const float4 a =
                    *reinterpret_cast<const float4*>(&sb[i * 128 + qs]);
                acc[i][0] = fmaf(a.x, w0.x, fmaf(a.y, w0.y,
                            fmaf(a.z, w0.z, fmaf(a.w, w0.w, acc[i][0]))));
                acc[i][1] = fmaf(a.x, w1.x, fmaf(a.y, w1.y,
                            fmaf(a.z, w1.z, fmaf(a.w, w1.w, acc[i][1]))));
            }
        }
    };

    issue_loads(0);
    write_smem(0);
    __syncthreads();
    for (int kc = 0; kc < 16; ++kc) {
        if (kc < 15) issue_loads(kc + 1);
        compute(kc, kc & 1);
        __syncthreads();
        if (kc < 15) {
            write_smem((kc + 1) & 1);
            __syncthreads();
        }
    }

    const float* bih = dir ? bihb : bihf;
    const float* bhh = dir ? bhhb : bhhf;
    const float bb0 = bih[j0] + bhh[j0];
    const float bb1 = bih[j0 + 1] + bhh[j0 + 1];

#pragma unroll
    for (int i = 0; i < 4; ++i) {
        const int m = mg * 4 + i;
        smem[c0 * 65 + m]       = acc[i][0] + bb0;
        smem[(c0 + 1) * 65 + m] = acc[i][1] + bb1;
    }
    __syncthreads();

    float* cslot = out + (dir ? OUT_CTB : OUT_CTF);
    float* hslot = out + (dir ? OUT_HTB : OUT_HTF);
    const float* cinit = dir ? c0b : c0f;
#pragma unroll
    for (int s2 = 0; s2 < 2; ++s2) {
        const int cell = s2 * 256 + tid;
        const int du = cell >> 6;
        const int m = cell & 63;
        const int u = u0 + du;
        const float ig = smem[(0 * 8 + du) * 65 + m];
        const float fg = smem[(1 * 8 + du) * 65 + m];
        const float gg = smem[(2 * 8 + du) * 65 + m];
        const float og = smem[(3 * 8 + du) * 65 + m];
        const float cp = (step == 0) ? cinit[m * H_DIM + u]
                                     : cslot[m * H_DIM + u];
        const float cn = sigmoidf_(fg) * cp + sigmoidf_(ig) * tanhf(gg);
        const float h  = sigmoidf_(og) * tanhf(cn);
        cslot[m * H_DIM + u] = cn;
        out[(size_t)t * B_DIM * 2 * H_DIM + m * 2 * H_DIM + dir * H_DIM + u] = h;
        if (step == T_DIM - 1) hslot[m * H_DIM + u] = h;
    }
}

extern "C" void kernel_launch(void* const* d_in, const int* in_sizes, int n_in,
                              void* d_out, int out_size, void* d_ws, size_t ws_size,
                              hipStream_t stream)
{
    const float* x    = (const float*)d_in[0];
    const float* h0f  = (const float*)d_in[1];
    const float* c0f  = (const float*)d_in[2];
    const float* h0b  = (const float*)d_in[3];
    const float* c0b  = (const float*)d_in[4];
    const float* wihf = (const float*)d_in[5];
    const float* whhf = (const float*)d_in[6];
    const float* bihf = (const float*)d_in[7];
    const float* bhhf = (const float*)d_in[8];
    const float* wihb = (const float*)d_in[9];
    const float* whhb = (const float*)d_in[10];
    const float* bihb = (const float*)d_in[11];
    const float* bhhb = (const float*)d_in[12];
    float* out = (float*)d_out;

    const size_t GX_ELEMS = 2ull * 32768ull * 4096ull;
    const size_t NEED_F32 = GX_ELEMS * 4ull;   // 1 GiB
    const size_t NEED_B16 = GX_ELEMS * 2ull;   // 512 MiB

    if (ws_size >= NEED_F32) {
        float* gx = (float*)d_ws;
        xproj_gemm<float><<<dim3(64, 512), 256, 0, stream>>>(
            x, wihf, bihf, bhhf, wihb, bihb, bhhb, gx);
        for (int s = 0; s < T_DIM; ++s) {
            lstm_step_h<float><<<dim3(512), 256, 0, stream>>>(
                h0f, c0f, h0b, c0b, whhf, whhb, gx, out, s);
        }
    } else if (ws_size >= NEED_B16) {
        __hip_bfloat16* gx = (__hip_bfloat16*)d_ws;
        xproj_gemm<__hip_bfloat16><<<dim3(64, 512), 256, 0, stream>>>(
            x, wihf, bihf, bhhf, wihb, bihb, bhhb, gx);
        for (int s = 0; s < T_DIM; ++s) {
            lstm_step_h<__hip_bfloat16><<<dim3(512), 256, 0, stream>>>(
                h0f, c0f, h0b, c0b, whhf, whhb, gx, out, s);
        }
    } else {
        for (int s = 0; s < T_DIM; ++s) {
            lstm_step_mono<<<dim3(256), dim3(256), 0, stream>>>(
                x, h0f, c0f, h0b, c0b,
                wihf, whhf, bihf, bhhf,
                wihb, whhb, bihb, bhhb,
                out, s);
        }
    }
}